// Round 8
// baseline (32212.402 us; speedup 1.0000x reference)
//
#include <hip/hip_runtime.h>
#include <math.h>
#include <float.h>

#define BN   2
#define NPTS 16384
#define MPTS 4096
#define KGN  32
#define CIN  64
#define CLN  64
#define FPSB 4      // sub-blocks per batch for FPS
#define PPT  4      // points per thread in FPS (16384 / (4*1024))

// ---------- exact fp32 helpers (no FMA contraction; must match np fp32) ----------
__device__ __forceinline__ float exadd(float a, float b) {
#pragma clang fp contract(off)
    float r = a + b; return r;
}
__device__ __forceinline__ float exsub(float a, float b) {
#pragma clang fp contract(off)
    float r = a - b; return r;
}
__device__ __forceinline__ float exmul(float a, float b) {
#pragma clang fp contract(off)
    float r = a * b; return r;
}

__device__ __forceinline__ float wave_sum64(float v) {
#pragma unroll
    for (int off = 1; off < 64; off <<= 1) v += __shfl_xor(v, off);
    return v;
}

// =====================================================================
// K0: pack points as float4(x, y, z, ||p||^2) once. sb order matches
// jnp.sum(b*b,-1): ((x*x + y*y) + z*z), contract off. Values verbatim.
// =====================================================================
__global__ __launch_bounds__(256) void prep_kernel(const float* __restrict__ xyz,
                                                   float4* __restrict__ pts4) {
    const int i = blockIdx.x * 256 + threadIdx.x;   // 0 .. BN*NPTS-1
    const float x = xyz[3 * i + 0];
    const float y = xyz[3 * i + 1];
    const float z = xyz[3 * i + 2];
    const float sb = exadd(exadd(exmul(x, x), exmul(y, y)), exmul(z, z));
    pts4[i] = make_float4(x, y, z, sb);
}

// =====================================================================
// K1: FPS, multi-block. Per-point arithmetic identical to R3..R7
// (passed 5x): exact chain d = ((dx*dx + dy*dy) + dz*dz), dist=min,
// global argmax first-index.
// R7 post-mortem: allocator hard-caps this kernel near 56 VGPRs; 64
// live coords+dists cannot fit -> ~196 KB/iter L2 re-fetch (~3.5K cyc)
// dominated R4-R7. Fix: 4 blocks per batch, 4 pts/thread -> persistent
// state = 16 VGPRs, fits trivially, zero per-iter memory traffic.
// Cross-block combine via gen-tagged packed word in d_ws:
//   word = [gen=m+1 : bits 46..58][f32 dist bits : 14..45][idx^0x3FFF : 0..13]
// - release store / acquire load, agent scope (XCD-safe).
// - gen tag self-invalidates 0xAA poison (gen field 174762 != m+1) and
//   stale parity data (gen = m != m+1): no init kernel needed.
// - parity double-buffer: publishing iter m+2 overwrites the m slot,
//   legal because finishing m+1 required every block to have consumed m.
// Winner selection chain (in-thread strict >, wave f32-max + ballot
// lowest attaining lane, u64 (val<<32|~idx) 16-partial butterfly) is
// verbatim R7; one extra exact lex-compare merges the 4 block winners
// (block index ranges ordered; idx tie-break preserved).
// =====================================================================
__global__ __launch_bounds__(1024) void fps_kernel(const float4* __restrict__ P4,
                                                   int* __restrict__ out_idx,
                                                   unsigned long long* __restrict__ slots) {
    const int bb  = blockIdx.x >> 2;        // batch 0..1
    const int blk = blockIdx.x & 3;         // sub-block 0..3
    const int t   = threadIdx.x;
    const float4* P = P4 + (size_t)bb * NPTS;
    const int base = blk * (NPTS / FPSB) + t * PPT;   // this thread's first point

    float px[PPT], py[PPT], pz[PPT], dist[PPT];
#pragma unroll
    for (int i = 0; i < PPT; ++i) {
        float4 a = P[base + i];
        px[i] = a.x;
        py[i] = a.y;
        pz[i] = a.z;
        dist[i] = 1e10f;
    }

    __shared__ unsigned long long swave[2][16];

    int pidx = 0;                       // current farthest point (batch-global index)
    float4 cen = P[0];

    for (int m = 0; m < MPTS; ++m) {
        if (t == 0 && blk == 0) out_idx[bb * MPTS + m] = pidx;

        const float cx = cen.x, cy = cen.y, cz = cen.z;
        float lmax = -1.0f;
        int   argp = 0;
#pragma unroll
        for (int i = 0; i < PPT; ++i) {
            float dx = exsub(px[i], cx);
            float dy = exsub(py[i], cy);
            float dz = exsub(pz[i], cz);
            float d  = exadd(exadd(exmul(dx, dx), exmul(dy, dy)), exmul(dz, dz));
            float nd = fminf(dist[i], d);
            dist[i] = nd;
            if (nd > lmax) { lmax = nd; argp = base + i; }  // strict > : first index
        }
        // ---- wave level: f32 max + ballot (distances >= 0, no NaN) ----
        float wmax = lmax;
#pragma unroll
        for (int off = 1; off < 64; off <<= 1) wmax = fmaxf(wmax, __shfl_xor(wmax, off));
        const unsigned long long att = __ballot(lmax == wmax);
        const int lsrc = __ffsll(att) - 1;                  // lowest attaining lane
        const int widx = __shfl(argp, lsrc);                // wave's smallest attaining idx
        // ---- block level: u64 (val hi, ~idx lo) over 16 partials ----
        const unsigned long long pk =
            ((unsigned long long)__float_as_uint(wmax) << 32) |
            (unsigned long long)(0xFFFFFFFFu - (unsigned)widx);
        if ((t & 63) == 0) swave[m & 1][t >> 6] = pk;
        __syncthreads();
        unsigned long long w = swave[m & 1][t & 15];
#pragma unroll
        for (int off = 1; off < 16; off <<= 1) {
            unsigned long long o = __shfl_xor(w, off);
            w = (o > w) ? o : w;
        }
        unsigned bval = (unsigned)(w >> 32);
        int      bidx = (int)(0xFFFFFFFFu - (unsigned)(w & 0xFFFFFFFFull));

        // ---- grid level: publish block winner, spin-merge the other 3 ----
        const unsigned long long word =
            ((unsigned long long)(unsigned)(m + 1) << 46) |
            ((unsigned long long)bval << 14) |
            (unsigned long long)(0x3FFFu ^ (unsigned)bidx);
        if (t == 0) {
            __hip_atomic_store(&slots[(bb * FPSB + blk) * 2 + (m & 1)], word,
                               __ATOMIC_RELEASE, __HIP_MEMORY_SCOPE_AGENT);
        }
        unsigned cval = bval; int cidx = bidx;
#pragma unroll
        for (int o = 1; o < FPSB; ++o) {
            const int rb = blk ^ o;                         // the other three blocks
            unsigned long long rw;
            do {
                rw = __hip_atomic_load(&slots[(bb * FPSB + rb) * 2 + (m & 1)],
                                       __ATOMIC_ACQUIRE, __HIP_MEMORY_SCOPE_AGENT);
            } while ((rw >> 46) != (unsigned long long)(m + 1));
            const unsigned rval = (unsigned)((rw >> 14) & 0xFFFFFFFFull);
            const int      ridx = (int)(0x3FFFu ^ (unsigned)(rw & 0x3FFFull));
            if (rval > cval || (rval == cval && ridx < cidx)) { cval = rval; cidx = ridx; }
        }
        pidx = cidx;
        cen = P[pidx];                                      // same-address broadcast load
    }
}

// =====================================================================
// K2: exact 32-NN, wave per centroid, NO per-lane arrays (verbatim R4).
// Wave-wide sorted top-32 in one (key,idx) register pair per lane;
// ballot + popc-rank insert; radius pre-filter (set-equivalent, see R4).
// =====================================================================
__global__ __launch_bounds__(256) void knn_kernel(const float4* __restrict__ pts4,
                                                  const int* __restrict__ fps_idx,
                                                  float* __restrict__ newxyz,
                                                  int* __restrict__ nn_idx,
                                                  float* __restrict__ nn_key) {
    const int lane = threadIdx.x & 63;
    const int g    = blockIdx.x * 4 + (threadIdx.x >> 6);   // centroid 0..8191
    const int b    = g >> 12;
    const float4* P = pts4 + (size_t)b * NPTS;

    const int far = fps_idx[g];
    const float4 C = P[far];
    if (lane == 0) {
        newxyz[g * 3 + 0] = C.x;
        newxyz[g * 3 + 1] = C.y;
        newxyz[g * 3 + 2] = C.z;
    }
    const float sa = C.w;

    float skey = FLT_MAX;   // lanes 0..31: sorted entries; lanes 32..63: inert
    int   sidx = 0;

    for (int it = 0; it < NPTS / 64; ++it) {
        const int j = it * 64 + lane;
        const float4 Q = P[j];
        const float dot = exadd(exadd(exmul(C.x, Q.x), exmul(C.y, Q.y)), exmul(C.z, Q.z));
        const float d2  = exsub(exadd(sa, Q.w), exadd(dot, dot));
        const float dk  = fmaxf(d2, 0.0f);
        const float tk = __shfl(skey, 31);
        const int   ti = __shfl(sidx, 31);
        const bool pass = (sqrtf(dk) <= 0.8f) &&
                          ((dk < tk) || (dk == tk && j < ti));
        unsigned long long mask = __ballot(pass);
        while (mask) {
            const int src = __ffsll(mask) - 1;
            mask &= mask - 1;
            const float ck = __shfl(dk, src);
            const int   cj = it * 64 + src;
            const bool less = (skey < ck) || (skey == ck && sidx < cj);
            const int p = __popcll(__ballot(less));   // wave-uniform rank
            if (p < 32) {                              // wave-uniform branch
                const float upk = __shfl_up(skey, 1);
                const int   upi = __shfl_up(sidx, 1);
                if (lane < 32) {
                    if (lane == p)     { skey = ck;  sidx = cj; }
                    else if (lane > p) { skey = upk; sidx = upi; }
                }
            }
        }
    }
    if (lane < KGN) {
        nn_idx[(size_t)g * KGN + lane] = sidx;
        nn_key[(size_t)g * KGN + lane] = skey;
    }
}

// =====================================================================
// K3: shared MLP 3->32->32->64 (+BN affine +ReLU), radius mask via
// sqrtf(nn_key) <= 0.8, max over 32 neighbors (verbatim R4..R7).
// =====================================================================
__global__ __attribute__((amdgpu_waves_per_eu(4, 4)))
__launch_bounds__(256) void mlp_kernel(const float* __restrict__ xyz,
                                       const float* __restrict__ w1, const float* __restrict__ s1, const float* __restrict__ b1,
                                       const float* __restrict__ w2, const float* __restrict__ s2, const float* __restrict__ b2,
                                       const float* __restrict__ w3, const float* __restrict__ s3, const float* __restrict__ b3,
                                       const float* __restrict__ newxyz,
                                       const int* __restrict__ nn_idx,
                                       const float* __restrict__ nn_key,
                                       float* __restrict__ FLout) {
    __shared__ float W1[96], S1[32], B1[32];
    __shared__ float W2[1024], S2[32], B2[32];
    __shared__ float W3[2048], S3[64], B3[64];
    const int tid = threadIdx.x;
    for (int i = tid; i < 96; i += 256)   W1[i] = w1[i];
    for (int i = tid; i < 32; i += 256) { S1[i] = s1[i]; B1[i] = b1[i]; S2[i] = s2[i]; B2[i] = b2[i]; }
    for (int i = tid; i < 1024; i += 256) W2[i] = w2[i];
    for (int i = tid; i < 2048; i += 256) W3[i] = w3[i];
    for (int i = tid; i < 64; i += 256) { S3[i] = s3[i]; B3[i] = b3[i]; }
    __syncthreads();

    const int n  = tid & 31;
    const int g  = blockIdx.x * 8 + (tid >> 5);   // centroid 0..8191
    const int b  = g >> 12;
    const size_t base = (size_t)g * KGN + n;
    const int   nj = nn_idx[base];
    const float nk = nn_key[base];

    const float* X = xyz + (size_t)b * NPTS * 3;
    const float gx = X[nj * 3 + 0] - newxyz[g * 3 + 0];
    const float gy = X[nj * 3 + 1] - newxyz[g * 3 + 1];
    const float gz = X[nj * 3 + 2] - newxyz[g * 3 + 2];

    float h1[32];
#pragma unroll
    for (int o = 0; o < 32; ++o) {
        float a = gx * W1[o * 3 + 0] + gy * W1[o * 3 + 1] + gz * W1[o * 3 + 2];
        h1[o] = fmaxf(a * S1[o] + B1[o], 0.0f);
    }
    float h2[32];
#pragma unroll
    for (int o = 0; o < 32; ++o) {
        float a = 0.0f;
#pragma unroll
        for (int k = 0; k < 32; ++k) a += h1[k] * W2[o * 32 + k];
        h2[o] = fmaxf(a * S2[o] + B2[o], 0.0f);
    }
    const bool valid = (sqrtf(nk) <= 0.8f);   // exact mask (sentinel FLT_MAX -> false)

    for (int o = 0; o < 64; ++o) {
        float a = 0.0f;
#pragma unroll
        for (int k = 0; k < 32; ++k) a += h2[k] * W3[o * 32 + k];
        float v = fmaxf(a * S3[o] + B3[o], 0.0f);
        v = valid ? v : -INFINITY;
#pragma unroll
        for (int off = 1; off < 32; off <<= 1) v = fmaxf(v, __shfl_xor(v, off));
        if (n == (o & 31)) FLout[(size_t)g * CLN + o] = v;
    }
}

// =====================================================================
// K4: DAM fusion (verbatim R7, incl. validated stride-65 padding that
// removed the 2.4e7 LDS bank-conflict cycles).
// =====================================================================
__global__ __launch_bounds__(256) void fuse_kernel(const float* __restrict__ pts_cam,
                                                   const float* __restrict__ FIn,
                                                   const float* __restrict__ tw1, const float* __restrict__ tb1,
                                                   const float* __restrict__ tw2, const float* __restrict__ tb2,
                                                   const float* __restrict__ tw3, const float* __restrict__ tb3,
                                                   const float* __restrict__ gw_raw, const float* __restrict__ gb_raw,
                                                   const float* __restrict__ gw_img, const float* __restrict__ gb_img,
                                                   const float* __restrict__ gw_lid, const float* __restrict__ gb_lid,
                                                   const float* __restrict__ uw, const float* __restrict__ ub,
                                                   const float* __restrict__ vw, const float* __restrict__ vb,
                                                   const int* __restrict__ fps_idx,
                                                   const float* __restrict__ newxyz,
                                                   const float* __restrict__ FLin,
                                                   float* __restrict__ out) {
    __shared__ float WIm[64 * 65], WLi[64 * 65], WT2[64 * 65];
    const int tid = threadIdx.x;
    for (int i = tid; i < 4096; i += 256) {
        int c = i >> 6, k = i & 63;          // weight[c][k] -> transposed [k][c], stride 65
        WIm[k * 65 + c] = gw_img[i];
        WLi[k * 65 + c] = gw_lid[i];
        WT2[k * 65 + c] = tw2[i];
    }
    __syncthreads();

    const int lane = tid & 63;
    const int g    = blockIdx.x * 4 + (tid >> 6);   // centroid 0..8191
    const int b    = g >> 12;
    const int m    = g & (MPTS - 1);
    const int far  = fps_idx[g];

    const float fi_in = FIn[((size_t)(b * CIN + lane)) * NPTS + far];
    const float fl_in = FLin[(size_t)g * CLN + lane];
    const float nx = newxyz[g * 3 + 0], ny = newxyz[g * 3 + 1], nz = newxyz[g * 3 + 2];

    float fr = fmaxf(nx * gw_raw[lane * 3 + 0] + ny * gw_raw[lane * 3 + 1] +
                     nz * gw_raw[lane * 3 + 2] + gb_raw[lane], 0.0f);

    float ai = gb_img[lane], al = gb_lid[lane];
#pragma unroll 8
    for (int k = 0; k < 64; ++k) {
        float vi = __shfl(fi_in, k);
        float vl = __shfl(fl_in, k);
        ai += vi * WIm[k * 65 + lane];
        al += vl * WLi[k * 65 + lane];
    }
    const float s = tanhf(fr + fmaxf(ai, 0.0f) + fmaxf(al, 0.0f));

    // AdaptiveThresholdNet on constant density
    const float dens = (float)(64.0 / (4.0 / 3.0 * 3.14159 * 1.0));
    float t1 = fmaxf(dens * tw1[lane] + tb1[lane], 0.0f);
    float a2 = tb2[lane];
#pragma unroll 8
    for (int k = 0; k < 64; ++k) a2 += __shfl(t1, k) * WT2[k * 65 + lane];
    float t2 = fmaxf(a2, 0.0f);
    float a3 = wave_sum64(t2 * tw3[lane]) + tb3[0];
    float thr = 20.0f + 40.0f * (1.0f / (1.0f + expf(-a3)));

    float aI = wave_sum64(s * uw[lane]) + ub[0];
    float aL = wave_sum64(s * vw[lane]) + vb[0];
    float wIv = 1.0f / (1.0f + expf(-aI));
    float wLv = 1.0f / (1.0f + expf(-aL));

    const float z = pts_cam[((size_t)b * NPTS + far) * 3 + 2];
    const bool near = (z <= thr);

    const size_t o1 = ((size_t)(b * 128 + lane)) * MPTS + m;
    out[o1]                       = near ? fl_in        : fi_in;
    out[o1 + (size_t)64 * MPTS]   = near ? fi_in * wIv  : fl_in * wLv;
}

// =====================================================================
extern "C" void kernel_launch(void* const* d_in, const int* in_sizes, int n_in,
                              void* d_out, int out_size, void* d_ws, size_t ws_size,
                              hipStream_t stream) {
    const float* xyz     = (const float*)d_in[0];
    const float* pts_cam = (const float*)d_in[1];
    const float* FI      = (const float*)d_in[2];
    const float* w1 = (const float*)d_in[3];
    const float* s1 = (const float*)d_in[4];
    const float* b1 = (const float*)d_in[5];
    const float* w2 = (const float*)d_in[6];
    const float* s2 = (const float*)d_in[7];
    const float* b2 = (const float*)d_in[8];
    const float* w3 = (const float*)d_in[9];
    const float* s3 = (const float*)d_in[10];
    const float* b3 = (const float*)d_in[11];
    const float* tw1 = (const float*)d_in[12];
    const float* tb1 = (const float*)d_in[13];
    const float* tw2 = (const float*)d_in[14];
    const float* tb2 = (const float*)d_in[15];
    const float* tw3 = (const float*)d_in[16];
    const float* tb3 = (const float*)d_in[17];
    const float* gw_raw = (const float*)d_in[18];
    const float* gb_raw = (const float*)d_in[19];
    const float* gw_img = (const float*)d_in[20];
    const float* gb_img = (const float*)d_in[21];
    const float* gw_lid = (const float*)d_in[22];
    const float* gb_lid = (const float*)d_in[23];
    const float* uw = (const float*)d_in[24];
    const float* ub = (const float*)d_in[25];
    const float* vw = (const float*)d_in[26];
    const float* vb = (const float*)d_in[27];
    float* out = (float*)d_out;

    // workspace layout (bytes) — total 4,325,376.
    // pts4 dead after knn; FL aliases it. fps sync slots live in the first
    // 64 B of the nn_key region (knn writes nn_key only AFTER fps completes
    // — stream-ordered, no temporal overlap).
    char* ws = (char*)d_ws;
    int*    ws_idx    = (int*)   (ws + 0);         // 8192 ints    (32 KB)
    float*  ws_newxyz = (float*) (ws + 32768);     // 24576 f      (96 KB)  -> 131072
    float4* ws_pts4   = (float4*)(ws + 131072);    // 32768 float4 (512 KB) -> 655360 [dead after knn]
    float*  ws_FL     = (float*) (ws + 131072);    // 524288 f     (2 MB)   -> 2228224 [aliases pts4]
    int*    ws_nnidx  = (int*)   (ws + 2228224);   // 262144 ints  (1 MB)   -> 3276800
    float*  ws_nnkey  = (float*) (ws + 3276800);   // 262144 f     (1 MB)   -> 4325376
    unsigned long long* ws_slots = (unsigned long long*)(ws + 3276800);  // 16 u64, overlaps nn_key head (time-disjoint)
    (void)ws_size; (void)in_sizes; (void)n_in; (void)out_size;

    prep_kernel<<<(BN * NPTS) / 256, 256, 0, stream>>>(xyz, ws_pts4);
    fps_kernel<<<BN * FPSB, 1024, 0, stream>>>(ws_pts4, ws_idx, ws_slots);
    knn_kernel<<<2048, 256, 0, stream>>>(ws_pts4, ws_idx, ws_newxyz, ws_nnidx, ws_nnkey);
    mlp_kernel<<<1024, 256, 0, stream>>>(xyz, w1, s1, b1, w2, s2, b2, w3, s3, b3,
                                         ws_newxyz, ws_nnidx, ws_nnkey, ws_FL);
    fuse_kernel<<<2048, 256, 0, stream>>>(pts_cam, FI, tw1, tb1, tw2, tb2, tw3, tb3,
                                          gw_raw, gb_raw, gw_img, gb_img, gw_lid, gb_lid,
                                          uw, ub, vw, vb, ws_idx, ws_newxyz, ws_FL, out);
}

// Round 9
// 8256.385 us; speedup vs baseline: 3.9015x; 3.9015x over previous
//
#include <hip/hip_runtime.h>
#include <math.h>
#include <float.h>

#define BN   2
#define NPTS 16384
#define MPTS 4096
#define KGN  32
#define CIN  64
#define CLN  64

// ---------- exact fp32 helpers (no FMA contraction; must match np fp32) ----------
__device__ __forceinline__ float exadd(float a, float b) {
#pragma clang fp contract(off)
    float r = a + b; return r;
}
__device__ __forceinline__ float exsub(float a, float b) {
#pragma clang fp contract(off)
    float r = a - b; return r;
}
__device__ __forceinline__ float exmul(float a, float b) {
#pragma clang fp contract(off)
    float r = a * b; return r;
}

__device__ __forceinline__ float wave_sum64(float v) {
#pragma unroll
    for (int off = 1; off < 64; off <<= 1) v += __shfl_xor(v, off);
    return v;
}

// =====================================================================
// K0: pack points as float4(x, y, z, ||p||^2) once. sb order matches
// jnp.sum(b*b,-1): ((x*x + y*y) + z*z), contract off. Values verbatim.
// =====================================================================
__global__ __launch_bounds__(256) void prep_kernel(const float* __restrict__ xyz,
                                                   float4* __restrict__ pts4) {
    const int i = blockIdx.x * 256 + threadIdx.x;   // 0 .. BN*NPTS-1
    const float x = xyz[3 * i + 0];
    const float y = xyz[3 * i + 1];
    const float z = xyz[3 * i + 2];
    const float sb = exadd(exadd(exmul(x, x), exmul(y, y)), exmul(z, z));
    pts4[i] = make_float4(x, y, z, sb);
}

// =====================================================================
// K1: FPS, single block per batch. Per-point arithmetic + winner
// selection identical to R7 (passed): exact chain
// d = ((dx*dx + dy*dy) + dz*dz), dist = min(dist,d); in-thread strict->
// argmax (first index); f32 wave-max + lowest-attaining-lane ballot;
// u64 (val<<32|~idx) 16-partial butterfly after ONE barrier (parity
// double-buffered partials — validated R6/R7/R8).
// Storage (the R4..R8 ledger): allocator caps this kernel at ~52 VGPRs;
// 64 live values re-fetch 256 KB/iter from L2 (~64 B/cyc/CU) = the 4.1K
// cyc/iter floor seen since R4. Split state to FIT 52 regs:
//   * pz[16] + dist[16] in registers (32 persistent + temps ~= 50).
//   * (x,y) in 128 KB LDS — and each thread reads ONLY ITS OWN entries,
//     so sxy is a private non-spillable store: no barrier, no cross-
//     thread hazard, conflict-free at the b64 structural minimum.
// No pins (R6: bunched reloads), no dead LDS, no RA attributes (R7:
// neutral). Zero per-iter global traffic except the 1x cen broadcast.
// =====================================================================
__global__ __launch_bounds__(1024) void fps_kernel(const float4* __restrict__ P4,
                                                   int* __restrict__ out_idx) {
    const int b = blockIdx.x;
    const int t = threadIdx.x;
    const float4* P = P4 + (size_t)b * NPTS;

    __shared__ float2 sxy[NPTS];                 // 128 KB, [i*1024 + t], thread-private
    __shared__ unsigned long long swave[2][16];  // parity-double-buffered partials

    float pz[16], dist[16];
#pragma unroll
    for (int i = 0; i < 16; ++i) {
        float4 a = P[t * 16 + i];
        sxy[i * 1024 + t] = make_float2(a.x, a.y);
        pz[i]  = a.z;
        dist[i] = 1e10f;
    }

    int pidx = 0;                       // current farthest point (batch-global index)
    float4 cen = P[0];

    for (int m = 0; m < MPTS; ++m) {
        if (t == 0) out_idx[b * MPTS + m] = pidx;

        const float cx = cen.x, cy = cen.y, cz = cen.z;
        float lmax = -1.0f;
        int   argp = 0;
#pragma unroll
        for (int i = 0; i < 16; ++i) {
            float2 xy = sxy[i * 1024 + t];       // own entry: no sync needed
            float dx = exsub(xy.x, cx);
            float dy = exsub(xy.y, cy);
            float dz = exsub(pz[i], cz);
            float d  = exadd(exadd(exmul(dx, dx), exmul(dy, dy)), exmul(dz, dz));
            float nd = fminf(dist[i], d);
            dist[i] = nd;
            if (nd > lmax) { lmax = nd; argp = t * 16 + i; }  // strict > : first index
        }
        // ---- wave level: f32 max + ballot (distances >= 0, no NaN) ----
        float wmax = lmax;
#pragma unroll
        for (int off = 1; off < 64; off <<= 1) wmax = fmaxf(wmax, __shfl_xor(wmax, off));
        const unsigned long long att = __ballot(lmax == wmax);
        const int lsrc = __ffsll(att) - 1;                  // lowest attaining lane
        const int widx = __shfl(argp, lsrc);                // wave's smallest attaining idx
        // ---- block level: u64 (val hi, ~idx lo) over 16 partials ----
        const unsigned long long pk =
            ((unsigned long long)__float_as_uint(wmax) << 32) |
            (unsigned long long)(0xFFFFFFFFu - (unsigned)widx);
        if ((t & 63) == 0) swave[m & 1][t >> 6] = pk;
        __syncthreads();
        unsigned long long w = swave[m & 1][t & 15];
#pragma unroll
        for (int off = 1; off < 16; off <<= 1) {
            unsigned long long o = __shfl_xor(w, off);
            w = (o > w) ? o : w;
        }
        pidx = (int)(0xFFFFFFFFu - (unsigned)(w & 0xFFFFFFFFull));
        cen = P[pidx];                                      // same-address broadcast load
    }
}

// =====================================================================
// K2: exact 32-NN, wave per centroid, NO per-lane arrays (verbatim R4).
// Wave-wide sorted top-32 in one (key,idx) register pair per lane;
// ballot + popc-rank insert; radius pre-filter (set-equivalent, see R4).
// =====================================================================
__global__ __launch_bounds__(256) void knn_kernel(const float4* __restrict__ pts4,
                                                  const int* __restrict__ fps_idx,
                                                  float* __restrict__ newxyz,
                                                  int* __restrict__ nn_idx,
                                                  float* __restrict__ nn_key) {
    const int lane = threadIdx.x & 63;
    const int g    = blockIdx.x * 4 + (threadIdx.x >> 6);   // centroid 0..8191
    const int b    = g >> 12;
    const float4* P = pts4 + (size_t)b * NPTS;

    const int far = fps_idx[g];
    const float4 C = P[far];
    if (lane == 0) {
        newxyz[g * 3 + 0] = C.x;
        newxyz[g * 3 + 1] = C.y;
        newxyz[g * 3 + 2] = C.z;
    }
    const float sa = C.w;

    float skey = FLT_MAX;   // lanes 0..31: sorted entries; lanes 32..63: inert
    int   sidx = 0;

    for (int it = 0; it < NPTS / 64; ++it) {
        const int j = it * 64 + lane;
        const float4 Q = P[j];
        const float dot = exadd(exadd(exmul(C.x, Q.x), exmul(C.y, Q.y)), exmul(C.z, Q.z));
        const float d2  = exsub(exadd(sa, Q.w), exadd(dot, dot));
        const float dk  = fmaxf(d2, 0.0f);
        const float tk = __shfl(skey, 31);
        const int   ti = __shfl(sidx, 31);
        const bool pass = (sqrtf(dk) <= 0.8f) &&
                          ((dk < tk) || (dk == tk && j < ti));
        unsigned long long mask = __ballot(pass);
        while (mask) {
            const int src = __ffsll(mask) - 1;
            mask &= mask - 1;
            const float ck = __shfl(dk, src);
            const int   cj = it * 64 + src;
            const bool less = (skey < ck) || (skey == ck && sidx < cj);
            const int p = __popcll(__ballot(less));   // wave-uniform rank
            if (p < 32) {                              // wave-uniform branch
                const float upk = __shfl_up(skey, 1);
                const int   upi = __shfl_up(sidx, 1);
                if (lane < 32) {
                    if (lane == p)     { skey = ck;  sidx = cj; }
                    else if (lane > p) { skey = upk; sidx = upi; }
                }
            }
        }
    }
    if (lane < KGN) {
        nn_idx[(size_t)g * KGN + lane] = sidx;
        nn_key[(size_t)g * KGN + lane] = skey;
    }
}

// =====================================================================
// K3: shared MLP 3->32->32->64 (+BN affine +ReLU), radius mask via
// sqrtf(nn_key) <= 0.8, max over 32 neighbors (verbatim R4..R8).
// =====================================================================
__global__ __attribute__((amdgpu_waves_per_eu(4, 4)))
__launch_bounds__(256) void mlp_kernel(const float* __restrict__ xyz,
                                       const float* __restrict__ w1, const float* __restrict__ s1, const float* __restrict__ b1,
                                       const float* __restrict__ w2, const float* __restrict__ s2, const float* __restrict__ b2,
                                       const float* __restrict__ w3, const float* __restrict__ s3, const float* __restrict__ b3,
                                       const float* __restrict__ newxyz,
                                       const int* __restrict__ nn_idx,
                                       const float* __restrict__ nn_key,
                                       float* __restrict__ FLout) {
    __shared__ float W1[96], S1[32], B1[32];
    __shared__ float W2[1024], S2[32], B2[32];
    __shared__ float W3[2048], S3[64], B3[64];
    const int tid = threadIdx.x;
    for (int i = tid; i < 96; i += 256)   W1[i] = w1[i];
    for (int i = tid; i < 32; i += 256) { S1[i] = s1[i]; B1[i] = b1[i]; S2[i] = s2[i]; B2[i] = b2[i]; }
    for (int i = tid; i < 1024; i += 256) W2[i] = w2[i];
    for (int i = tid; i < 2048; i += 256) W3[i] = w3[i];
    for (int i = tid; i < 64; i += 256) { S3[i] = s3[i]; B3[i] = b3[i]; }
    __syncthreads();

    const int n  = tid & 31;
    const int g  = blockIdx.x * 8 + (tid >> 5);   // centroid 0..8191
    const int b  = g >> 12;
    const size_t base = (size_t)g * KGN + n;
    const int   nj = nn_idx[base];
    const float nk = nn_key[base];

    const float* X = xyz + (size_t)b * NPTS * 3;
    const float gx = X[nj * 3 + 0] - newxyz[g * 3 + 0];
    const float gy = X[nj * 3 + 1] - newxyz[g * 3 + 1];
    const float gz = X[nj * 3 + 2] - newxyz[g * 3 + 2];

    float h1[32];
#pragma unroll
    for (int o = 0; o < 32; ++o) {
        float a = gx * W1[o * 3 + 0] + gy * W1[o * 3 + 1] + gz * W1[o * 3 + 2];
        h1[o] = fmaxf(a * S1[o] + B1[o], 0.0f);
    }
    float h2[32];
#pragma unroll
    for (int o = 0; o < 32; ++o) {
        float a = 0.0f;
#pragma unroll
        for (int k = 0; k < 32; ++k) a += h1[k] * W2[o * 32 + k];
        h2[o] = fmaxf(a * S2[o] + B2[o], 0.0f);
    }
    const bool valid = (sqrtf(nk) <= 0.8f);   // exact mask (sentinel FLT_MAX -> false)

    for (int o = 0; o < 64; ++o) {
        float a = 0.0f;
#pragma unroll
        for (int k = 0; k < 32; ++k) a += h2[k] * W3[o * 32 + k];
        float v = fmaxf(a * S3[o] + B3[o], 0.0f);
        v = valid ? v : -INFINITY;
#pragma unroll
        for (int off = 1; off < 32; off <<= 1) v = fmaxf(v, __shfl_xor(v, off));
        if (n == (o & 31)) FLout[(size_t)g * CLN + o] = v;
    }
}

// =====================================================================
// K4: DAM fusion (verbatim R7/R8, incl. validated stride-65 padding
// that removed the 2.4e7 LDS bank-conflict cycles).
// =====================================================================
__global__ __launch_bounds__(256) void fuse_kernel(const float* __restrict__ pts_cam,
                                                   const float* __restrict__ FIn,
                                                   const float* __restrict__ tw1, const float* __restrict__ tb1,
                                                   const float* __restrict__ tw2, const float* __restrict__ tb2,
                                                   const float* __restrict__ tw3, const float* __restrict__ tb3,
                                                   const float* __restrict__ gw_raw, const float* __restrict__ gb_raw,
                                                   const float* __restrict__ gw_img, const float* __restrict__ gb_img,
                                                   const float* __restrict__ gw_lid, const float* __restrict__ gb_lid,
                                                   const float* __restrict__ uw, const float* __restrict__ ub,
                                                   const float* __restrict__ vw, const float* __restrict__ vb,
                                                   const int* __restrict__ fps_idx,
                                                   const float* __restrict__ newxyz,
                                                   const float* __restrict__ FLin,
                                                   float* __restrict__ out) {
    __shared__ float WIm[64 * 65], WLi[64 * 65], WT2[64 * 65];
    const int tid = threadIdx.x;
    for (int i = tid; i < 4096; i += 256) {
        int c = i >> 6, k = i & 63;          // weight[c][k] -> transposed [k][c], stride 65
        WIm[k * 65 + c] = gw_img[i];
        WLi[k * 65 + c] = gw_lid[i];
        WT2[k * 65 + c] = tw2[i];
    }
    __syncthreads();

    const int lane = tid & 63;
    const int g    = blockIdx.x * 4 + (tid >> 6);   // centroid 0..8191
    const int b    = g >> 12;
    const int m    = g & (MPTS - 1);
    const int far  = fps_idx[g];

    const float fi_in = FIn[((size_t)(b * CIN + lane)) * NPTS + far];
    const float fl_in = FLin[(size_t)g * CLN + lane];
    const float nx = newxyz[g * 3 + 0], ny = newxyz[g * 3 + 1], nz = newxyz[g * 3 + 2];

    float fr = fmaxf(nx * gw_raw[lane * 3 + 0] + ny * gw_raw[lane * 3 + 1] +
                     nz * gw_raw[lane * 3 + 2] + gb_raw[lane], 0.0f);

    float ai = gb_img[lane], al = gb_lid[lane];
#pragma unroll 8
    for (int k = 0; k < 64; ++k) {
        float vi = __shfl(fi_in, k);
        float vl = __shfl(fl_in, k);
        ai += vi * WIm[k * 65 + lane];
        al += vl * WLi[k * 65 + lane];
    }
    const float s = tanhf(fr + fmaxf(ai, 0.0f) + fmaxf(al, 0.0f));

    // AdaptiveThresholdNet on constant density
    const float dens = (float)(64.0 / (4.0 / 3.0 * 3.14159 * 1.0));
    float t1 = fmaxf(dens * tw1[lane] + tb1[lane], 0.0f);
    float a2 = tb2[lane];
#pragma unroll 8
    for (int k = 0; k < 64; ++k) a2 += __shfl(t1, k) * WT2[k * 65 + lane];
    float t2 = fmaxf(a2, 0.0f);
    float a3 = wave_sum64(t2 * tw3[lane]) + tb3[0];
    float thr = 20.0f + 40.0f * (1.0f / (1.0f + expf(-a3)));

    float aI = wave_sum64(s * uw[lane]) + ub[0];
    float aL = wave_sum64(s * vw[lane]) + vb[0];
    float wIv = 1.0f / (1.0f + expf(-aI));
    float wLv = 1.0f / (1.0f + expf(-aL));

    const float z = pts_cam[((size_t)b * NPTS + far) * 3 + 2];
    const bool near = (z <= thr);

    const size_t o1 = ((size_t)(b * 128 + lane)) * MPTS + m;
    out[o1]                       = near ? fl_in        : fi_in;
    out[o1 + (size_t)64 * MPTS]   = near ? fi_in * wIv  : fl_in * wLv;
}

// =====================================================================
extern "C" void kernel_launch(void* const* d_in, const int* in_sizes, int n_in,
                              void* d_out, int out_size, void* d_ws, size_t ws_size,
                              hipStream_t stream) {
    const float* xyz     = (const float*)d_in[0];
    const float* pts_cam = (const float*)d_in[1];
    const float* FI      = (const float*)d_in[2];
    const float* w1 = (const float*)d_in[3];
    const float* s1 = (const float*)d_in[4];
    const float* b1 = (const float*)d_in[5];
    const float* w2 = (const float*)d_in[6];
    const float* s2 = (const float*)d_in[7];
    const float* b2 = (const float*)d_in[8];
    const float* w3 = (const float*)d_in[9];
    const float* s3 = (const float*)d_in[10];
    const float* b3 = (const float*)d_in[11];
    const float* tw1 = (const float*)d_in[12];
    const float* tb1 = (const float*)d_in[13];
    const float* tw2 = (const float*)d_in[14];
    const float* tb2 = (const float*)d_in[15];
    const float* tw3 = (const float*)d_in[16];
    const float* tb3 = (const float*)d_in[17];
    const float* gw_raw = (const float*)d_in[18];
    const float* gb_raw = (const float*)d_in[19];
    const float* gw_img = (const float*)d_in[20];
    const float* gb_img = (const float*)d_in[21];
    const float* gw_lid = (const float*)d_in[22];
    const float* gb_lid = (const float*)d_in[23];
    const float* uw = (const float*)d_in[24];
    const float* ub = (const float*)d_in[25];
    const float* vw = (const float*)d_in[26];
    const float* vb = (const float*)d_in[27];
    float* out = (float*)d_out;

    // workspace layout (bytes) — total 4,325,376.
    // pts4 dead after knn; FL aliases it.
    char* ws = (char*)d_ws;
    int*    ws_idx    = (int*)   (ws + 0);         // 8192 ints    (32 KB)
    float*  ws_newxyz = (float*) (ws + 32768);     // 24576 f      (96 KB)  -> 131072
    float4* ws_pts4   = (float4*)(ws + 131072);    // 32768 float4 (512 KB) -> 655360 [dead after knn]
    float*  ws_FL     = (float*) (ws + 131072);    // 524288 f     (2 MB)   -> 2228224 [aliases pts4]
    int*    ws_nnidx  = (int*)   (ws + 2228224);   // 262144 ints  (1 MB)   -> 3276800
    float*  ws_nnkey  = (float*) (ws + 3276800);   // 262144 f     (1 MB)   -> 4325376
    (void)ws_size; (void)in_sizes; (void)n_in; (void)out_size;

    prep_kernel<<<(BN * NPTS) / 256, 256, 0, stream>>>(xyz, ws_pts4);
    fps_kernel<<<BN, 1024, 0, stream>>>(ws_pts4, ws_idx);
    knn_kernel<<<2048, 256, 0, stream>>>(ws_pts4, ws_idx, ws_newxyz, ws_nnidx, ws_nnkey);
    mlp_kernel<<<1024, 256, 0, stream>>>(xyz, w1, s1, b1, w2, s2, b2, w3, s3, b3,
                                         ws_newxyz, ws_nnidx, ws_nnkey, ws_FL);
    fuse_kernel<<<2048, 256, 0, stream>>>(pts_cam, FI, tw1, tb1, tw2, tb2, tw3, tb3,
                                          gw_raw, gb_raw, gw_img, gb_img, gw_lid, gb_lid,
                                          uw, ub, vw, vb, ws_idx, ws_newxyz, ws_FL, out);
}